// Round 13
// baseline (181.843 us; speedup 1.0000x reference)
//
#include <hip/hip_runtime.h>
#include <hip/hip_bf16.h>
#include <stdint.h>

typedef __attribute__((ext_vector_type(4))) float f32x4;
typedef __attribute__((ext_vector_type(8))) short short8;
typedef __attribute__((ext_vector_type(4))) int int4v;

#define IN_F   8192
#define OUT_F  8192
#define MROWS  256
#define NGRP   128
#define QROW   4096  // int32s per q_weight row
#define PROW   1024  // packed dwords per row
#define NSLICE 4
#define KT_PER 32    // 4*32*64 = 8192 = full K

__device__ unsigned short g_xb[MROWS * IN_F];             // 4 MB bf16 x, fragment-major (k-permuted)
__device__ uint32_t       g_qp[OUT_F * PROW];             // 33.5 MB packed q (1B/weight-pair)
__device__ float          g_t[MROWS * 16];
__device__ float          g_part[NSLICE * MROWS * OUT_F]; // 32 MB split-K partials

static __device__ inline uint32_t pkbf(float a, float b) {
  __bf16 ha = (__bf16)a, hb = (__bf16)b;
  return (uint32_t)__builtin_bit_cast(unsigned short, ha)
       | ((uint32_t)__builtin_bit_cast(unsigned short, hb) << 16);
}

// ---- k_pack: q int32 (low byte) -> packed bytes, 16 ints -> 16B per thread
__global__ __launch_bounds__(256) void k_pack(const int* __restrict__ qw) {
  size_t t = (size_t)blockIdx.x * 256 + threadIdx.x;
  const int* src = qw + t * 16;
  int4v o;
#pragma unroll
  for (int d = 0; d < 4; ++d) {
    int4v q = *(const int4v*)(src + d * 4);
    uint32_t p01 = __builtin_amdgcn_perm((uint32_t)q[1], (uint32_t)q[0], 0x00000400u);
    uint32_t p23 = __builtin_amdgcn_perm((uint32_t)q[3], (uint32_t)q[2], 0x00000400u);
    o[d] = (int)__builtin_amdgcn_perm(p23, p01, 0x05040100u);
  }
  *(int4v*)(g_qp + t * 4) = o;
}

// ---- k0: x fp32 -> bf16, fragment-major, k-permuted [0,2,4,6,1,3,5,7] within each 8
__global__ __launch_bounds__(256) void k_convert(const float* __restrict__ x) {
  int d = blockIdx.x * 256 + threadIdx.x;
  int l15 = d & 15, sub = (d >> 4) & 3, kk = (d >> 6) & 1;
  int m16 = (d >> 7) & 15, kt = d >> 11;
  int r = m16 * 16 + l15;
  int k = kt * 64 + (kk * 4 + sub) * 8;
  const float* src = x + (size_t)r * IN_F + k;
  f32x4 v0 = *(const f32x4*)src;
  f32x4 v1 = *(const f32x4*)(src + 4);
  int4v ov;
  ov[0] = (int)pkbf(v0.x, v0.z);
  ov[1] = (int)pkbf(v1.x, v1.z);
  ov[2] = (int)pkbf(v0.y, v0.w);
  ov[3] = (int)pkbf(v1.y, v1.w);
  *(int4v*)(g_xb + (size_t)d * 8) = ov;
}

// ---- k1: g_t = 2 * x @ lora_A^T
__global__ __launch_bounds__(256) void k_xa(const float* __restrict__ x,
                                            const float* __restrict__ lora_A) {
  int m = blockIdx.x, tid = threadIdx.x;
  float acc[16];
#pragma unroll
  for (int r = 0; r < 16; ++r) acc[r] = 0.f;
  const float* xr = x + (size_t)m * IN_F;
  for (int it = 0; it < 8; ++it) {
    int k = (tid + it * 256) * 4;
    f32x4 xv = *(const f32x4*)(xr + k);
#pragma unroll
    for (int r = 0; r < 16; ++r) {
      f32x4 av = *(const f32x4*)(lora_A + (size_t)r * IN_F + k);
      acc[r] += xv.x * av.x + xv.y * av.y + xv.z * av.z + xv.w * av.w;
    }
  }
#pragma unroll
  for (int r = 0; r < 16; ++r) {
    float v = acc[r];
#pragma unroll
    for (int off = 32; off; off >>= 1) v += __shfl_xor(v, off, 64);
    acc[r] = v;
  }
  __shared__ float sm[4][16];
  int lane = tid & 63, wave = tid >> 6;
  if (lane == 0) {
#pragma unroll
    for (int r = 0; r < 16; ++r) sm[wave][r] = acc[r];
  }
  __syncthreads();
  if (tid < 16)
    g_t[m * 16 + tid] = 2.0f * (sm[0][tid] + sm[1][tid] + sm[2][tid] + sm[3][tid]);
}

// VALU NF4 dequant: one packed dword (4 bytes = 8 weights) -> 8 bf16, permuted k-order.
static __device__ inline int4v dq8p(uint32_t pk4,
                                    uint32_t hiT1, uint32_t hiT0,
                                    uint32_t loT1, uint32_t loT0) {
  uint32_t nh = (pk4 >> 4) & 0x0F0F0F0Fu;
  uint32_t nl = pk4 & 0x0F0F0F0Fu;

  uint32_t nb3H = (~nh) & 0x08080808u;
  uint32_t m7H  = nb3H - (nb3H >> 3);
  uint32_t mgH  = (nh ^ m7H) & 0x07070707u;
  uint32_t sgH  = nb3H << 4;
  uint32_t hibH = __builtin_amdgcn_perm(hiT1, hiT0, mgH) | sgH;
  uint32_t lobH = __builtin_amdgcn_perm(loT1, loT0, mgH);

  uint32_t nb3L = (~nl) & 0x08080808u;
  uint32_t m7L  = nb3L - (nb3L >> 3);
  uint32_t mgL  = (nl ^ m7L) & 0x07070707u;
  uint32_t sgL  = nb3L << 4;
  uint32_t hibL = __builtin_amdgcn_perm(hiT1, hiT0, mgL) | sgL;
  uint32_t lobL = __builtin_amdgcn_perm(loT1, loT0, mgL);

  int4v r;
  r[0] = (int)__builtin_amdgcn_perm(hibH, lobH, 0x05010400u);
  r[1] = (int)__builtin_amdgcn_perm(hibH, lobH, 0x07030602u);
  r[2] = (int)__builtin_amdgcn_perm(hibL, lobL, 0x05010400u);
  r[3] = (int)__builtin_amdgcn_perm(hibL, lobL, 0x07030602u);
  return r;
}

// ---- k3: main GEMM. 256 blocks (1/CU) x 512 thr = 8 waves (4M x 2N), per-wave 64x64.
// Zero LDS / zero barriers. q: packed dwords (L3) depth-2 prefetch; A: L2 depth-1;
// VALU dequant; scale folded post-MFMA in fp32.
__global__ __launch_bounds__(512, 2) void k_gemm(const float* __restrict__ scales) {
  int tid = threadIdx.x;
  int lane = tid & 63, wave = tid >> 6;

  const float mags[8] = {0.04209530f, 0.12734085f, 0.21594601f, 0.31090474f,
                         0.41681853f, 0.54221982f, 0.70756721f, 1.0f};
  uint32_t loT0 = 0, loT1 = 0, hiT0 = 0, hiT1 = 0;
#pragma unroll
  for (int i = 0; i < 4; ++i) {
    uint32_t b = pkbf(mags[i], 0.f) & 0xFFFFu;
    loT0 |= (b & 0xFFu) << (8 * i); hiT0 |= (b >> 8) << (8 * i);
  }
#pragma unroll
  for (int i = 0; i < 4; ++i) {
    uint32_t b = pkbf(mags[4 + i], 0.f) & 0xFFFFu;
    loT1 |= (b & 0xFFu) << (8 * i); hiT1 |= (b >> 8) << (8 * i);
  }

  int flat = blockIdx.x;
  int wg = (flat & 7) * 32 + (flat >> 3);
  int bx = wg & 63, bz = wg >> 6;
  int n0 = bx * 128;
  int ktg0 = bz * KT_PER;

  int wr = wave >> 1, wc = wave & 1;
  int sub = lane >> 4, l15 = lane & 15;

  const uint32_t* qp[4];
  const float* sp[4];
#pragma unroll
  for (int ni = 0; ni < 4; ++ni) {
    size_t rowb = (size_t)(n0 + wc * 64 + ni * 16 + l15);
    qp[ni] = g_qp + rowb * PROW + sub;
    sp[ni] = scales + rowb * NGRP;
  }
  const unsigned short* abase =
      g_xb + (size_t)(wr * 4) * 1024 + (sub * 16 + l15) * 8;

  f32x4 acc[4][4];
#pragma unroll
  for (int i = 0; i < 4; ++i)
#pragma unroll
    for (int j = 0; j < 4; ++j) acc[i][j] = (f32x4){0.f, 0.f, 0.f, 0.f};

  // prologue: q/s for t0 and t1; A for t0
  uint32_t qb[8], qn[8];
  float sb[4], sn[4];
#pragma unroll
  for (int ni = 0; ni < 4; ++ni) {
#pragma unroll
    for (int kk = 0; kk < 2; ++kk) {
      qb[ni * 2 + kk] = qp[ni][(size_t)ktg0 * 8 + kk * 4];
      qn[ni * 2 + kk] = qp[ni][(size_t)(ktg0 + 1) * 8 + kk * 4];
    }
    sb[ni] = sp[ni][ktg0];
    sn[ni] = sp[ni][ktg0 + 1];
  }
  short8 af[2][4];
  {
    const unsigned short* ab = abase + (size_t)ktg0 * 16384;
#pragma unroll
    for (int kk = 0; kk < 2; ++kk)
#pragma unroll
      for (int mi = 0; mi < 4; ++mi)
        af[kk][mi] = *(const short8*)(ab + mi * 1024 + kk * 512);
  }

#pragma clang loop unroll(disable)
  for (int t = 0; t < KT_PER; ++t) {
    int ktg = ktg0 + t;

    // A prefetch for t+1 (L2), q/s prefetch for t+2 (L3) — issue before compute
    int ta = (t < KT_PER - 1) ? (ktg + 1) : ktg;
    short8 afn[2][4];
    const unsigned short* abn = abase + (size_t)ta * 16384;
#pragma unroll
    for (int kk = 0; kk < 2; ++kk)
#pragma unroll
      for (int mi = 0; mi < 4; ++mi)
        afn[kk][mi] = *(const short8*)(abn + mi * 1024 + kk * 512);

    int tq = (t < KT_PER - 2) ? (ktg + 2) : ktg;
    uint32_t qn2[8]; float sn2[4];
#pragma unroll
    for (int ni = 0; ni < 4; ++ni) {
#pragma unroll
      for (int kk = 0; kk < 2; ++kk)
        qn2[ni * 2 + kk] = qp[ni][(size_t)tq * 8 + kk * 4];
      sn2[ni] = sp[ni][tq];
    }

    // dequant + MFMA + scale fold
#pragma unroll
    for (int ni = 0; ni < 4; ++ni) {
      int4v b0 = dq8p(qb[ni * 2 + 0], hiT1, hiT0, loT1, loT0);
      int4v b1 = dq8p(qb[ni * 2 + 1], hiT1, hiT0, loT1, loT0);
      f32x4 tacc[4];
#pragma unroll
      for (int mi = 0; mi < 4; ++mi) tacc[mi] = (f32x4){0.f, 0.f, 0.f, 0.f};
      __builtin_amdgcn_s_setprio(1);
      short8 bs0 = __builtin_bit_cast(short8, b0);
#pragma unroll
      for (int mi = 0; mi < 4; ++mi)
        tacc[mi] = __builtin_amdgcn_mfma_f32_16x16x32_bf16(af[0][mi], bs0, tacc[mi], 0, 0, 0);
      short8 bs1 = __builtin_bit_cast(short8, b1);
#pragma unroll
      for (int mi = 0; mi < 4; ++mi)
        tacc[mi] = __builtin_amdgcn_mfma_f32_16x16x32_bf16(af[1][mi], bs1, tacc[mi], 0, 0, 0);
      __builtin_amdgcn_s_setprio(0);
      float s = sb[ni];
#pragma unroll
      for (int mi = 0; mi < 4; ++mi) {
        acc[mi][ni].x += s * tacc[mi].x;
        acc[mi][ni].y += s * tacc[mi].y;
        acc[mi][ni].z += s * tacc[mi].z;
        acc[mi][ni].w += s * tacc[mi].w;
      }
    }

    // rotate pipelines
#pragma unroll
    for (int kk = 0; kk < 2; ++kk)
#pragma unroll
      for (int mi = 0; mi < 4; ++mi) af[kk][mi] = afn[kk][mi];
#pragma unroll
    for (int i = 0; i < 8; ++i) { qb[i] = qn[i]; qn[i] = qn2[i]; }
#pragma unroll
    for (int i = 0; i < 4; ++i) { sb[i] = sn[i]; sn[i] = sn2[i]; }
  }

  // epilogue -> per-slice partials. D layout: col=lane&15, row=(lane>>4)*4+reg
  float* op = g_part + (size_t)bz * MROWS * OUT_F;
#pragma unroll
  for (int mi = 0; mi < 4; ++mi) {
#pragma unroll
    for (int ni = 0; ni < 4; ++ni) {
      int m = wr * 64 + mi * 16 + sub * 4;
      int nn = n0 + wc * 64 + ni * 16 + l15;
#pragma unroll
      for (int j = 0; j < 4; ++j)
        op[(size_t)(m + j) * OUT_F + nn] = acc[mi][ni][j];
    }
  }
}

// ---- k4: out = sum of 4 split-K partials + LoRA (g_t @ lora_B^T), fused
__global__ __launch_bounds__(256) void k_reduce(const float* __restrict__ lora_B,
                                                float* __restrict__ out) {
  size_t i = ((size_t)blockIdx.x * 256 + threadIdx.x) * 4;
  int m = (int)(i >> 13);
  int n = (int)(i & 8191);
  f32x4 v = *(const f32x4*)(g_part + i);
#pragma unroll
  for (int s = 1; s < NSLICE; ++s)
    v += *(const f32x4*)(g_part + (size_t)s * MROWS * OUT_F + i);
  const float* tr = g_t + m * 16;
  f32x4 t0 = *(const f32x4*)tr,       t1 = *(const f32x4*)(tr + 4);
  f32x4 t2 = *(const f32x4*)(tr + 8), t3 = *(const f32x4*)(tr + 12);
#pragma unroll
  for (int j = 0; j < 4; ++j) {
    const float* br = lora_B + (size_t)(n + j) * 16;
    f32x4 b0 = *(const f32x4*)br,       b1 = *(const f32x4*)(br + 4);
    f32x4 b2 = *(const f32x4*)(br + 8), b3 = *(const f32x4*)(br + 12);
    v[j] += t0.x*b0.x + t0.y*b0.y + t0.z*b0.z + t0.w*b0.w
          + t1.x*b1.x + t1.y*b1.y + t1.z*b1.z + t1.w*b1.w
          + t2.x*b2.x + t2.y*b2.y + t2.z*b2.z + t2.w*b2.w
          + t3.x*b3.x + t3.y*b3.y + t3.z*b3.z + t3.w*b3.w;
  }
  *(f32x4*)(out + i) = v;
}

extern "C" void kernel_launch(void* const* d_in, const int* in_sizes, int n_in,
                              void* d_out, int out_size, void* d_ws, size_t ws_size,
                              hipStream_t stream) {
  const float* x  = (const float*)d_in[0];
  const int*   qw = (const int*)d_in[1];
  const float* sc = (const float*)d_in[2];
  const float* lA = (const float*)d_in[3];
  const float* lB = (const float*)d_in[4];
  float* out = (float*)d_out;

  k_pack<<<8192, 256, 0, stream>>>(qw);
  k_convert<<<1024, 256, 0, stream>>>(x);
  k_xa<<<256, 256, 0, stream>>>(x, lA);
  k_gemm<<<256, 512, 0, stream>>>(sc);
  k_reduce<<<2048, 256, 0, stream>>>(lB, out);
}